// Round 4
// baseline (667.961 us; speedup 1.0000x reference)
//
#include <hip/hip_runtime.h>
#include <hip/hip_bf16.h>
#include <math.h>

#define B_DIM 65536
#define N_DIM 1024
#define BMR 64          // batch rows per block
#define BN  128         // output cols per block
#define BK  64
#define NKT (N_DIM / BK)   // 16
#define THREADS 256
#define DT_C 0.01f
#define NS_SCALE 0.01f  // NOISE_STD * sqrt(DT)

typedef __attribute__((ext_vector_type(8))) short bf16x8;
typedef __attribute__((ext_vector_type(4))) float f32x4;

__device__ __forceinline__ unsigned short f2bf(float f) {
    union { float f; unsigned int u; } a;
    a.f = f;
    unsigned int r = a.u + 0x7fffu + ((a.u >> 16) & 1u);
    return (unsigned short)(r >> 16);
}
__device__ __forceinline__ float bf2f(unsigned short u) {
    union { unsigned int u; float f; } a;
    a.u = ((unsigned int)u) << 16;
    return a.f;
}

__device__ __forceinline__ void gload_lds16(const void* g, void* l) {
    __builtin_amdgcn_global_load_lds(
        (const __attribute__((address_space(1))) void*)g,
        (__attribute__((address_space(3))) void*)l, 16, 0, 0);
}

// K (fp32, row-major N x N) -> bf16
__global__ void k_convK(const float* __restrict__ K, unsigned short* __restrict__ Kbf) {
    int i = blockIdx.x * blockDim.x + threadIdx.x;
    float4 v = reinterpret_cast<const float4*>(K)[i];
    ushort4 o;
    o.x = f2bf(v.x); o.y = f2bf(v.y); o.z = f2bf(v.z); o.w = f2bf(v.w);
    reinterpret_cast<ushort4*>(Kbf)[i] = o;
}

// smem union (32768 ushorts = 64KB):
//   GEMM phase: sA [buf][set][g(8)][r(64)][8] = 16384 ushorts (32KB)
//               sB [buf][g(8)][row(128)][8]   = 16384 ushorts (32KB) @ +16384
//   epilogue:   eS [64][128] @ 0, eC [64][128] @ +8192 (bf16 acc exchange)
__device__ __forceinline__ int sAo(int buf, int set, int g, int r) {
    return (((buf * 2 + set) * 8 + g) * 64 + r) * 8;
}
__device__ __forceinline__ int sBo(int buf, int g, int row) {
    return 16384 + ((buf * 8 + g) * 128 + row) * 8;
}

// Set-split m97-style fused GEMM:
//   waves: ws = set (0=sin A, 1=cos A), wn = col half. Each wave: 64x64 tile,
//   acc[4][4] f32x4 (one set only). Epilogue exchanges Ks/Kc via LDS bf16.
__global__ __launch_bounds__(THREADS, 2)
void k_fused(const float* __restrict__ theta,
             const float* __restrict__ noise,
             const float* __restrict__ omega,
             const unsigned short* __restrict__ Kbf,
             float* __restrict__ out) {
    __shared__ unsigned short smem[32768];   // 64KB

    const int tid  = threadIdx.x;
    const int lane = tid & 63;
    const int w    = tid >> 6;     // wave 0..3
    const int ws   = w >> 1;       // 0 = sin-accum (Ks), 1 = cos-accum (Kc)
    const int wn   = w & 1;        // col half (64 cols)

    // XCD swizzle: the 8 col-tiles of a row-panel stay consecutive on one XCD
    const int nwg     = gridDim.x;          // 8192
    const int cpx     = nwg >> 3;           // 1024
    const int logical = (blockIdx.x & 7) * cpx + (blockIdx.x >> 3);
    const int mt      = logical >> 3;       // 0..1023
    const int nt      = logical & 7;        // 0..7
    const int row0    = mt * BMR;
    const int col0    = nt * BN;

    // A staging: thread -> (r, gp): 16 theta elems (k = kt*64 + gp*16 .. +16)
    const int r  = tid & 63;
    const int gp = tid >> 6;       // 0..3

    f32x4 acc[4][4];
#pragma unroll
    for (int mi = 0; mi < 4; ++mi)
#pragma unroll
        for (int ni = 0; ni < 4; ++ni)
            acc[mi][ni] = (f32x4){0.f, 0.f, 0.f, 0.f};

    auto stage = [&](int buf, int kt) {
        // ---- B: K tile (128 cols x 64 k, bf16) via global_load_lds ----
#pragma unroll
        for (int j = 0; j < 4; ++j) {
            const int s  = w * 4 + j;
            const int g  = s >> 1;
            const int hh = s & 1;
            const unsigned short* src =
                Kbf + (size_t)(col0 + hh * 64 + lane) * N_DIM + kt * BK + g * 8;
            gload_lds16(src, &smem[sBo(buf, g, hh * 64)]);
        }
        // ---- A: theta -> sincos -> bf16 granules ----
        const float* gpth = theta + (size_t)(row0 + r) * N_DIM + kt * BK + gp * 16;
        float4 v0 = *reinterpret_cast<const float4*>(gpth + 0);
        float4 v1 = *reinterpret_cast<const float4*>(gpth + 4);
        float4 v2 = *reinterpret_cast<const float4*>(gpth + 8);
        float4 v3 = *reinterpret_cast<const float4*>(gpth + 12);
        float sn[16], cn[16];
        const float* vv = &v0.x;  // v0..v3 are consecutive? not guaranteed; do explicitly
        float in[16] = {v0.x, v0.y, v0.z, v0.w, v1.x, v1.y, v1.z, v1.w,
                        v2.x, v2.y, v2.z, v2.w, v3.x, v3.y, v3.z, v3.w};
        (void)vv;
#pragma unroll
        for (int e = 0; e < 16; ++e) __sincosf(in[e], &sn[e], &cn[e]);
        ushort4 pk[2][4];  // [granule-half][quad] for sin then cos written separately
        // sin granules: 2gp (elems 0..7), 2gp+1 (elems 8..15)
#pragma unroll
        for (int gg = 0; gg < 2; ++gg) {
            ushort4 a, b;
            a.x = f2bf(sn[gg * 8 + 0]); a.y = f2bf(sn[gg * 8 + 1]);
            a.z = f2bf(sn[gg * 8 + 2]); a.w = f2bf(sn[gg * 8 + 3]);
            b.x = f2bf(sn[gg * 8 + 4]); b.y = f2bf(sn[gg * 8 + 5]);
            b.z = f2bf(sn[gg * 8 + 6]); b.w = f2bf(sn[gg * 8 + 7]);
            pk[gg][0] = a; pk[gg][1] = b;
            ushort4 c, d;
            c.x = f2bf(cn[gg * 8 + 0]); c.y = f2bf(cn[gg * 8 + 1]);
            c.z = f2bf(cn[gg * 8 + 2]); c.w = f2bf(cn[gg * 8 + 3]);
            d.x = f2bf(cn[gg * 8 + 4]); d.y = f2bf(cn[gg * 8 + 5]);
            d.z = f2bf(cn[gg * 8 + 6]); d.w = f2bf(cn[gg * 8 + 7]);
            pk[gg][2] = c; pk[gg][3] = d;
        }
#pragma unroll
        for (int gg = 0; gg < 2; ++gg) {
            ushort4* ps = reinterpret_cast<ushort4*>(&smem[sAo(buf, 0, 2 * gp + gg, r)]);
            ps[0] = pk[gg][0]; ps[1] = pk[gg][1];
            ushort4* pc = reinterpret_cast<ushort4*>(&smem[sAo(buf, 1, 2 * gp + gg, r)]);
            pc[0] = pk[gg][2]; pc[1] = pk[gg][3];
        }
    };

    auto compute = [&](int buf) {
        const int lr = lane & 15;
        const int kq = lane >> 4;
#pragma unroll
        for (int kk = 0; kk < 2; ++kk) {
            const int g = kk * 4 + kq;
            bf16x8 aF[4], bF[4];
#pragma unroll
            for (int mi = 0; mi < 4; ++mi)
                aF[mi] = *reinterpret_cast<const bf16x8*>(&smem[sAo(buf, ws, g, mi * 16 + lr)]);
#pragma unroll
            for (int ni = 0; ni < 4; ++ni)
                bF[ni] = *reinterpret_cast<const bf16x8*>(&smem[sBo(buf, g, wn * 64 + ni * 16 + lr)]);
#pragma unroll
            for (int mi = 0; mi < 4; ++mi)
#pragma unroll
                for (int ni = 0; ni < 4; ++ni)
                    acc[mi][ni] = __builtin_amdgcn_mfma_f32_16x16x32_bf16(aF[mi], bF[ni], acc[mi][ni], 0, 0, 0);
        }
    };

    stage(0, 0);
    __syncthreads();
    int cur = 0;
    for (int kt = 0; kt < NKT; ++kt) {
        if (kt + 1 < NKT) stage(cur ^ 1, kt + 1);
        compute(cur);
        __syncthreads();
        cur ^= 1;
    }

    // ---- epilogue: exchange acc via LDS (bf16), then fused elementwise ----
    // eS @ 0, eC @ 8192 (ushort offsets), layout [r(64)][c(128)]
    {
        const int lr = lane & 15;
        const int base = ws * 8192;
#pragma unroll
        for (int mi = 0; mi < 4; ++mi)
#pragma unroll
            for (int ni = 0; ni < 4; ++ni) {
                const int cc = wn * 64 + ni * 16 + lr;
#pragma unroll
                for (int v = 0; v < 4; ++v) {
                    const int rr = mi * 16 + (lane >> 4) * 4 + v;
                    smem[base + rr * 128 + cc] = f2bf(acc[mi][ni][v]);
                }
            }
    }
    __syncthreads();
#pragma unroll
    for (int p = 0; p < 8; ++p) {
        const int rr = p * 8 + (tid >> 5);
        const int c4 = (tid & 31) * 4;
        ushort4 us = *reinterpret_cast<ushort4*>(&smem[rr * 128 + c4]);
        ushort4 uc = *reinterpret_cast<ushort4*>(&smem[8192 + rr * 128 + c4]);
        const size_t gidx = (size_t)(row0 + rr) * N_DIM + col0 + c4;
        float4 th = *reinterpret_cast<const float4*>(&theta[gidx]);
        float4 nz = *reinterpret_cast<const float4*>(&noise[gidx]);
        float4 om = *reinterpret_cast<const float4*>(&omega[col0 + c4]);
        float4 o;
        {
            float s0, c0; __sincosf(th.x, &s0, &c0);
            o.x = th.x + (om.x + c0 * bf2f(us.x) - s0 * bf2f(uc.x)) * DT_C + nz.x * NS_SCALE;
        }
        {
            float s1, c1; __sincosf(th.y, &s1, &c1);
            o.y = th.y + (om.y + c1 * bf2f(us.y) - s1 * bf2f(uc.y)) * DT_C + nz.y * NS_SCALE;
        }
        {
            float s2, c2; __sincosf(th.z, &s2, &c2);
            o.z = th.z + (om.z + c2 * bf2f(us.z) - s2 * bf2f(uc.z)) * DT_C + nz.z * NS_SCALE;
        }
        {
            float s3, c3; __sincosf(th.w, &s3, &c3);
            o.w = th.w + (om.w + c3 * bf2f(us.w) - s3 * bf2f(uc.w)) * DT_C + nz.w * NS_SCALE;
        }
        *reinterpret_cast<float4*>(&out[gidx]) = o;
    }
}

extern "C" void kernel_launch(void* const* d_in, const int* in_sizes, int n_in,
                              void* d_out, int out_size, void* d_ws, size_t ws_size,
                              hipStream_t stream) {
    const float* theta = (const float*)d_in[0];
    const float* noise = (const float*)d_in[1];
    const float* omega = (const float*)d_in[2];
    const float* K     = (const float*)d_in[3];
    float* out = (float*)d_out;

    unsigned short* Kbf = (unsigned short*)d_ws;   // 2 MB

    k_convK<<<(N_DIM * N_DIM) / (256 * 4), 256, 0, stream>>>(K, Kbf);

    const int grid = (B_DIM / BMR) * (N_DIM / BN);  // 8192
    k_fused<<<grid, THREADS, 0, stream>>>(theta, noise, omega, Kbf, out);
}